// Round 12
// baseline (279.679 us; speedup 1.0000x reference)
//
#include <hip/hip_runtime.h>
#include <stdint.h>
#include <string.h>

// B=16, A=512, H=8, c = 512 - int(512*0.3) = 359
#define B_ 16
#define A_ 512
#define H_ 8
#define C_CROSS 359
#define LDSTRIDE 40  // ushorts per 32-k LDS row (80 B)

typedef short short8 __attribute__((ext_vector_type(8)));
typedef float floatx4 __attribute__((ext_vector_type(4)));

// ---------------- threefry2x32 (exact JAX partitionable semantics) ----------
__host__ __device__ __forceinline__ uint32_t rotl32(uint32_t x, int r) {
#ifdef __HIP_DEVICE_COMPILE__
  return __builtin_amdgcn_alignbit(x, x, 32 - r);
#else
  return (x << r) | (x >> (32 - r));
#endif
}

__host__ __device__ __forceinline__ void tf2x32(uint32_t k0, uint32_t k1,
                                                uint32_t x0, uint32_t x1,
                                                uint32_t& o0, uint32_t& o1) {
  uint32_t ks2 = k0 ^ k1 ^ 0x1BD11BDAu;
  x0 += k0; x1 += k1;
#define TFR(r) { x0 += x1; x1 = rotl32(x1, r); x1 ^= x0; }
  TFR(13) TFR(15) TFR(26) TFR(6)   x0 += k1;  x1 += ks2 + 1u;
  TFR(17) TFR(29) TFR(16) TFR(24)  x0 += ks2; x1 += k0 + 2u;
  TFR(13) TFR(15) TFR(26) TFR(6)   x0 += k0;  x1 += k1 + 3u;
  TFR(17) TFR(29) TFR(16) TFR(24)  x0 += k1;  x1 += ks2 + 4u;
  TFR(13) TFR(15) TFR(26) TFR(6)   x0 += ks2; x1 += k0 + 5u;
#undef TFR
  o0 = x0; o1 = x1;
}

__host__ __device__ __forceinline__ float bits2u01(uint32_t bits) {
  uint32_t v = (bits >> 9) | 0x3f800000u;
  float f;
#ifdef __HIP_DEVICE_COMPILE__
  f = __uint_as_float(v);
#else
  memcpy(&f, &v, 4);
#endif
  return f - 1.0f;
}

__device__ __forceinline__ float exp2_native(float x) {
  float r;
  asm("v_exp_f32 %0, %1\n\ts_nop 0" : "=v"(r) : "v"(x));
  return r;
}

// ---------------- truncation-split bf16 helpers ----------------
__device__ __forceinline__ void tsplit8(const float4& v0, const float4& v1,
                                        short8& h, short8& l) {
  float xs[8] = {v0.x, v0.y, v0.z, v0.w, v1.x, v1.y, v1.z, v1.w};
#pragma unroll
  for (int j = 0; j < 8; ++j) {
    uint32_t u = __float_as_uint(xs[j]);
    float hf = __uint_as_float(u & 0xffff0000u);
    h[j] = (short)(u >> 16);
    l[j] = (short)(__float_as_uint(xs[j] - hf) >> 16);
  }
}

// =====================================================================
// lin4: blocks 0..511 = 128x128 GEMM tile (X and W split in-kernel,
// register double-buffered); output TRANSPOSED + PRE-SPLIT bf16 hi/lo.
// blocks 512..543 = Vp GEMV (full-K, register acc, no atomics).
// =====================================================================
__global__ __launch_bounds__(256, 2) void lin4(
    const float* __restrict__ Xq, const float* __restrict__ Wq,
    const float* __restrict__ bq, ushort* __restrict__ QptH, ushort* __restrict__ QptL,
    const float* __restrict__ Xk, const float* __restrict__ Wk,
    const float* __restrict__ bk, ushort* __restrict__ KptH, ushort* __restrict__ KptL,
    const float* __restrict__ V, const float* __restrict__ WV_w,
    const float* __restrict__ WV_b, float* __restrict__ Vp) {
  __shared__ __align__(16) char smem[40960];
  int bid = blockIdx.x;
  int tid = threadIdx.x;

  if (bid >= 512) {
    // ---- Vp tail: Vp[b][j0+j] = WV_b[j0+j] + sum_k V[b][k]*WV_w[j0+j][k]
    int v = bid - 512;  // 0..31
    int j0 = v * 16;
    float* xs = (float*)smem;            // 16*260 floats
    float* wsh = (float*)(smem + 16640); // 16*260 floats
    int b = tid & 15, j = tid >> 4;
    float acc = WV_b[j0 + j];
    for (int kc = 0; kc < 2; ++kc) {
      int k0 = kc * 256;
      __syncthreads();
#pragma unroll
      for (int it = 0; it < 4; ++it) {
        int idx = it * 256 + tid;
        int rr = idx >> 6, kk4 = idx & 63;
        *(float4*)&xs[rr * 260 + kk4 * 4] =
            *(const float4*)(V + (size_t)rr * 512 + k0 + kk4 * 4);
        *(float4*)&wsh[rr * 260 + kk4 * 4] =
            *(const float4*)(WV_w + (size_t)(j0 + rr) * 512 + k0 + kk4 * 4);
      }
      __syncthreads();
      const float* xr = &xs[b * 260];
      const float* wr = &wsh[j * 260];
#pragma unroll
      for (int kk = 0; kk < 256; kk += 4) {
        float4 a = *(const float4*)(xr + kk);
        float4 w4 = *(const float4*)(wr + kk);
        acc += a.x * w4.x + a.y * w4.y + a.z * w4.z + a.w * w4.w;
      }
    }
    Vp[b * 512 + j0 + j] = acc;
    return;
  }

  // ---- GEMM tile ----
  int z = bid >> 8;
  int rem = bid & 255;
  int ti = rem >> 2, tn = rem & 3;
  const float* X = z ? Xk : Xq;
  const float* W = z ? Wk : Wq;
  const float* bias = z ? bk : bq;
  ushort* OH = z ? KptH : QptH;
  ushort* OL = z ? KptL : QptL;

  ushort (*Ah)[LDSTRIDE] = (ushort(*)[LDSTRIDE])(smem);
  ushort (*Al)[LDSTRIDE] = (ushort(*)[LDSTRIDE])(smem + 10240);
  ushort (*Bh)[LDSTRIDE] = (ushort(*)[LDSTRIDE])(smem + 20480);
  ushort (*Bl)[LDSTRIDE] = (ushort(*)[LDSTRIDE])(smem + 30720);
  uint32_t (*cs)[132] = (uint32_t(*)[132])(smem);  // epilogue alias

  int w = tid >> 6, lane = tid & 63, quad = lane >> 4, l16 = lane & 15;
  int wm = (w >> 1) * 64, wn = (w & 1) * 64;
  int m0 = ti * 128, n0 = tn * 128;

  float bv[4];
#pragma unroll
  for (int nt = 0; nt < 4; ++nt) bv[nt] = bias[n0 + wn + nt * 16 + l16];

  const float* pX[2];
  const float* pW[2];
  int mW[2], kgW[2];
#pragma unroll
  for (int g = 0; g < 2; ++g) {
    int gid = g * 256 + tid;
    int m = gid >> 2, kg = gid & 3;
    mW[g] = m; kgW[g] = kg;
    pX[g] = X + (size_t)(m0 + m) * 512 + kg * 8;
    pW[g] = W + (size_t)(n0 + m) * 512 + kg * 8;
  }

  float4 ra[2][2], rb[2][2];
#pragma unroll
  for (int g = 0; g < 2; ++g) {
    ra[g][0] = *(const float4*)(pX[g]);
    ra[g][1] = *(const float4*)(pX[g] + 4);
    rb[g][0] = *(const float4*)(pW[g]);
    rb[g][1] = *(const float4*)(pW[g] + 4);
  }

  floatx4 acc[4][4] = {};

  for (int k0 = 0; k0 < 512; k0 += 32) {
    __syncthreads();
#pragma unroll
    for (int g = 0; g < 2; ++g) {
      short8 h8, l8;
      tsplit8(ra[g][0], ra[g][1], h8, l8);
      *(short8*)&Ah[mW[g]][kgW[g] * 8] = h8;
      *(short8*)&Al[mW[g]][kgW[g] * 8] = l8;
      tsplit8(rb[g][0], rb[g][1], h8, l8);
      *(short8*)&Bh[mW[g]][kgW[g] * 8] = h8;
      *(short8*)&Bl[mW[g]][kgW[g] * 8] = l8;
    }
    __syncthreads();
    if (k0 < 480) {
      int kn = k0 + 32;
#pragma unroll
      for (int g = 0; g < 2; ++g) {
        ra[g][0] = *(const float4*)(pX[g] + kn);
        ra[g][1] = *(const float4*)(pX[g] + kn + 4);
        rb[g][0] = *(const float4*)(pW[g] + kn);
        rb[g][1] = *(const float4*)(pW[g] + kn + 4);
      }
    }
    short8 fAh[4], fAl[4], fBh[4], fBl[4];
#pragma unroll
    for (int t4 = 0; t4 < 4; ++t4) {
      int ma = wm + t4 * 16 + l16;
      int nb = wn + t4 * 16 + l16;
      fAh[t4] = *(const short8*)&Ah[ma][quad * 8];
      fAl[t4] = *(const short8*)&Al[ma][quad * 8];
      fBh[t4] = *(const short8*)&Bh[nb][quad * 8];
      fBl[t4] = *(const short8*)&Bl[nb][quad * 8];
    }
#pragma unroll
    for (int mt = 0; mt < 4; ++mt)
#pragma unroll
      for (int nt = 0; nt < 4; ++nt) {
        acc[mt][nt] = __builtin_amdgcn_mfma_f32_16x16x32_bf16(fAh[mt], fBh[nt], acc[mt][nt], 0, 0, 0);
        acc[mt][nt] = __builtin_amdgcn_mfma_f32_16x16x32_bf16(fAh[mt], fBl[nt], acc[mt][nt], 0, 0, 0);
        acc[mt][nt] = __builtin_amdgcn_mfma_f32_16x16x32_bf16(fAl[mt], fBh[nt], acc[mt][nt], 0, 0, 0);
      }
  }

  __syncthreads();
  int bb = m0 >> 9, i0 = m0 & 511;
  for (int p = 0; p < 2; ++p) {
    if ((w & 1) == p) {
#pragma unroll
      for (int mt = 0; mt < 4; ++mt)
#pragma unroll
        for (int nt = 0; nt < 4; ++nt)
#pragma unroll
          for (int rr = 0; rr < 4; ++rr) {
            float val = acc[mt][nt][rr] + bv[nt];
            uint32_t u = __float_as_uint(val);
            uint32_t hi = u & 0xffff0000u;
            uint32_t lo = __float_as_uint(val - __uint_as_float(hi)) >> 16;
            cs[nt * 16 + l16][wm + mt * 16 + quad * 4 + rr] = hi | lo;
          }
    }
    __syncthreads();
    {
      int col_l = tid >> 2, iseg = (tid & 3) * 32;
      int d = n0 + p * 64 + col_l;
      size_t obase = ((size_t)(bb * 512 + d)) * 512 + i0 + iseg;
      ushort* oh = OH + obase;
      ushort* ol = OL + obase;
#pragma unroll
      for (int sgi = 0; sgi < 4; ++sgi) {
        short8 hv, lv;
#pragma unroll
        for (int j = 0; j < 8; ++j) {
          uint32_t v = cs[col_l][iseg + sgi * 8 + j];
          hv[j] = (short)(v >> 16);
          lv[j] = (short)(v & 0xffffu);
        }
        *(short8*)(oh + sgi * 8) = hv;
        *(short8*)(ol + sgi * 8) = lv;
      }
    }
    __syncthreads();
  }
}

// =====================================================================
// am3: am0 = QK^T/sqrt(8); pre-split bf16 inputs; 128x128 tiles,
// XCD-swizzled grid (256); register double-buffered.
// =====================================================================
__global__ __launch_bounds__(256, 2) void am3(
    const ushort* __restrict__ QH, const ushort* __restrict__ QL,
    const ushort* __restrict__ KH, const ushort* __restrict__ KL,
    float* __restrict__ am0) {
  int bid = blockIdx.x;
  int xcd = bid & 7, slot = bid >> 3;
  int bz = xcd + 8 * (slot >> 4);
  int tt = slot & 15, ti = tt >> 2, tk = tt & 3;
  int bm0 = ti * 128, bn0 = tk * 128;
  size_t base = (size_t)bz * 262144;

  __shared__ __align__(16) char smem[40960];
  ushort (*Ah)[LDSTRIDE] = (ushort(*)[LDSTRIDE])(smem);
  ushort (*Al)[LDSTRIDE] = (ushort(*)[LDSTRIDE])(smem + 10240);
  ushort (*Bh)[LDSTRIDE] = (ushort(*)[LDSTRIDE])(smem + 20480);
  ushort (*Bl)[LDSTRIDE] = (ushort(*)[LDSTRIDE])(smem + 30720);

  int tid = threadIdx.x;
  int w = tid >> 6, lane = tid & 63, quad = lane >> 4, l16 = lane & 15;
  int wm = (w >> 1) * 64, wn = (w & 1) * 64;

  const ushort *pAH[2], *pAL[2], *pBH[2], *pBL[2];
  int mW[2], kgW[2];
#pragma unroll
  for (int g = 0; g < 2; ++g) {
    int gid = g * 256 + tid;
    int m = gid >> 2, kg = gid & 3;
    mW[g] = m; kgW[g] = kg;
    size_t offA = base + (size_t)(bm0 + m) * 512 + kg * 8;
    size_t offB = base + (size_t)(bn0 + m) * 512 + kg * 8;
    pAH[g] = QH + offA; pAL[g] = QL + offA;
    pBH[g] = KH + offB; pBL[g] = KL + offB;
  }

  short8 rah[2], ral[2], rbh[2], rbl[2];
#pragma unroll
  for (int g = 0; g < 2; ++g) {
    rah[g] = *(const short8*)(pAH[g]);
    ral[g] = *(const short8*)(pAL[g]);
    rbh[g] = *(const short8*)(pBH[g]);
    rbl[g] = *(const short8*)(pBL[g]);
  }

  floatx4 acc[4][4] = {};

  for (int k0 = 0; k0 < 512; k0 += 32) {
    __syncthreads();
#pragma unroll
    for (int g = 0; g < 2; ++g) {
      *(short8*)&Ah[mW[g]][kgW[g] * 8] = rah[g];
      *(short8*)&Al[mW[g]][kgW[g] * 8] = ral[g];
      *(short8*)&Bh[mW[g]][kgW[g] * 8] = rbh[g];
      *(short8*)&Bl[mW[g]][kgW[g] * 8] = rbl[g];
    }
    __syncthreads();
    if (k0 < 480) {
      int kn = k0 + 32;
#pragma unroll
      for (int g = 0; g < 2; ++g) {
        rah[g] = *(const short8*)(pAH[g] + kn);
        ral[g] = *(const short8*)(pAL[g] + kn);
        rbh[g] = *(const short8*)(pBH[g] + kn);
        rbl[g] = *(const short8*)(pBL[g] + kn);
      }
    }
    short8 fAh[4], fAl[4], fBh[4], fBl[4];
#pragma unroll
    for (int t4 = 0; t4 < 4; ++t4) {
      int ma = wm + t4 * 16 + l16;
      int nb = wn + t4 * 16 + l16;
      fAh[t4] = *(const short8*)&Ah[ma][quad * 8];
      fAl[t4] = *(const short8*)&Al[ma][quad * 8];
      fBh[t4] = *(const short8*)&Bh[nb][quad * 8];
      fBl[t4] = *(const short8*)&Bl[nb][quad * 8];
    }
#pragma unroll
    for (int mt = 0; mt < 4; ++mt)
#pragma unroll
      for (int nt = 0; nt < 4; ++nt) {
        acc[mt][nt] = __builtin_amdgcn_mfma_f32_16x16x32_bf16(fAh[mt], fBh[nt], acc[mt][nt], 0, 0, 0);
        acc[mt][nt] = __builtin_amdgcn_mfma_f32_16x16x32_bf16(fAh[mt], fBl[nt], acc[mt][nt], 0, 0, 0);
        acc[mt][nt] = __builtin_amdgcn_mfma_f32_16x16x32_bf16(fAl[mt], fBh[nt], acc[mt][nt], 0, 0, 0);
      }
  }
  const float scale = 0.35355339059327373f;  // 1/sqrt(8)
#pragma unroll
  for (int mt = 0; mt < 4; ++mt)
#pragma unroll
    for (int nt = 0; nt < 4; ++nt)
#pragma unroll
      for (int rr = 0; rr < 4; ++rr) {
        int row = bm0 + wm + mt * 16 + quad * 4 + rr;
        int col = bn0 + wn + nt * 16 + l16;
        am0[((size_t)(bz * 512 + row)) * 512 + col] = acc[mt][nt][rr] * scale;
      }
}

// ---------------- soft_mut: wave per (b,i) row, all 8 heads, inline hash ----
__global__ __launch_bounds__(256) void soft_mut(
    const float* __restrict__ am0, const float* __restrict__ Vp,
    float* __restrict__ oa, uint32_t km0, uint32_t km1) {
  int tid = threadIdx.x;
  int w = tid >> 6, lane = tid & 63;
  int rrow = blockIdx.x * 4 + w;  // b*512 + i
  int b = rrow >> 9, i = rrow & 511;
  int k0 = lane * 8;
  const float* ar = am0 + (((size_t)rrow) << 9) + k0;
  const float* vr = Vp + (b << 9) + k0;
  float4 a0 = *(const float4*)ar, a1 = *(const float4*)(ar + 4);
  float4 v0 = *(const float4*)vr, v1 = *(const float4*)(vr + 4);
  const float LOG2E = 1.4426950408889634f;
  float a2[8] = {a0.x * LOG2E, a0.y * LOG2E, a0.z * LOG2E, a0.w * LOG2E,
                 a1.x * LOG2E, a1.y * LOG2E, a1.z * LOG2E, a1.w * LOG2E};
  float vv[8] = {v0.x, v0.y, v0.z, v0.w, v1.x, v1.y, v1.z, v1.w};
  uint32_t Lbase = (uint32_t)b * 2097152u + (uint32_t)i * 512u + (uint32_t)k0;
  float outv[8];
#pragma unroll
  for (int h = 0; h < 8; ++h) {
    uint32_t Lh = Lbase + (uint32_t)h * 262144u;
    float s = 0.f, wsum = 0.f;
#pragma unroll
    for (int j = 0; j < 8; ++j) {  // 8 independent threefry chains -> ILP
      uint32_t o0, o1;
      tf2x32(km0, km1, 0u, Lh + (uint32_t)j, o0, o1);
      uint32_t bits = o0 ^ o1;
      float f = __uint_as_float((bits >> 9) | 0x3f800000u);
      float m = fmaxf(0.7f, __builtin_fmaf(f, 0.6f, 0.1f));
      float e = exp2_native(a2[j] * m);
      s += e;
      wsum += e * vv[j];
    }
#pragma unroll
    for (int o = 32; o; o >>= 1) { s += __shfl_xor(s, o); wsum += __shfl_xor(wsum, o); }
    outv[h] = wsum / s;
  }
  if (lane == 0) {
    int ob = (b << 12) + i;
#pragma unroll
    for (int h = 0; h < 8; ++h) oa[ob + (h << 9)] = outv[h];
  }
}

// ---------------- soft_cross ----------------
struct CrossCfg { int r1[B_ * H_]; int r2[B_ * H_]; };

__global__ __launch_bounds__(256) void soft_cross(
    const float* __restrict__ am0, const float* __restrict__ Vp,
    float* __restrict__ oa, CrossCfg cfg) {
  int tid = threadIdx.x;
  int w = tid >> 6, lane = tid & 63;
  int rrow = blockIdx.x * 4 + w;
  int b = rrow >> 12, h = (rrow >> 9) & 7, i = rrow & 511;
  int rr1 = cfg.r1[b * 8 + h], rr2 = cfg.r2[b * 8 + h];
  int src = (i == rr2) ? rr1 : ((i == rr1) ? rr2 : i);
  const float* ar = am0 + ((size_t)((b << 9) + i)) * A_;
  const float* ar2 = am0 + ((size_t)((b << 9) + src)) * A_;
  const float* vr = Vp + (b << 9);
  float s = 0.f, wsum = 0.f;
#pragma unroll
  for (int j = 0; j < 8; ++j) {
    int k = lane + 64 * j;
    float x = (k >= C_CROSS) ? ar2[k] : ar[k];
    float e = __expf(x);
    s += e;
    wsum += e * vr[k];
  }
#pragma unroll
  for (int o = 32; o; o >>= 1) { s += __shfl_xor(s, o); wsum += __shfl_xor(wsum, o); }
  if (lane == 0) oa[(((size_t)(b * 8 + h)) << 9) + i] = wsum / s;
}

// =====================================================================
// final_gemm: out[b][j0+j] = WO_b[j0+j] + sum_t oa[b][t]*WO_w[j0+j][t]
// grid 32; internal loop over 16 K-chunks; no atomics, no pre-zero.
// =====================================================================
__global__ __launch_bounds__(256) void final_gemm(
    const float* __restrict__ oa, const float* __restrict__ WO,
    const float* __restrict__ bias, float* __restrict__ out) {
  __shared__ float xs[16 * 260];
  __shared__ float wsh[16 * 260];
  int tid = threadIdx.x;
  int j0 = blockIdx.x * 16;
  int b = tid & 15, j = tid >> 4;
  float acc = bias[j0 + j];
  for (int kc = 0; kc < 16; ++kc) {
    int k0 = kc * 256;
    __syncthreads();
#pragma unroll
    for (int it = 0; it < 4; ++it) {
      int idx = it * 256 + tid;
      int rr = idx >> 6, kk4 = idx & 63;
      *(float4*)&xs[rr * 260 + kk4 * 4] =
          *(const float4*)(oa + (size_t)rr * 4096 + k0 + kk4 * 4);
      *(float4*)&wsh[rr * 260 + kk4 * 4] =
          *(const float4*)(WO + (size_t)(j0 + rr) * 4096 + k0 + kk4 * 4);
    }
    __syncthreads();
    const float* xr = &xs[b * 260];
    const float* wr = &wsh[j * 260];
#pragma unroll
    for (int kk = 0; kk < 256; kk += 4) {
      float4 a = *(const float4*)(xr + kk);
      float4 w4 = *(const float4*)(wr + kk);
      acc += a.x * w4.x + a.y * w4.y + a.z * w4.z + a.w * w4.w;
    }
  }
  out[b * 512 + j0 + j] = acc;
}

extern "C" void kernel_launch(void* const* d_in, const int* in_sizes, int n_in,
                              void* d_out, int out_size, void* d_ws, size_t ws_size,
                              hipStream_t stream) {
  (void)in_sizes; (void)n_in; (void)out_size; (void)ws_size;
  const float* Q    = (const float*)d_in[0];
  const float* K    = (const float*)d_in[1];
  const float* V    = (const float*)d_in[2];
  const float* WQ_w = (const float*)d_in[3];
  const float* WQ_b = (const float*)d_in[4];
  const float* WK_w = (const float*)d_in[5];
  const float* WK_b = (const float*)d_in[6];
  const float* WV_w = (const float*)d_in[7];
  const float* WV_b = (const float*)d_in[8];
  const float* WO_w = (const float*)d_in[9];
  const float* WO_b = (const float*)d_in[10];
  float* out = (float*)d_out;

  // ws: QptH/QptL/KptH/KptL (4 x 8.39MB) + am0 (16.78MB) + Vp(32KB) + oa(256KB)
  //   = 50.66MB (fits every prior tier)
  char* ws = (char*)d_ws;
  ushort* QptH = (ushort*)(ws);
  ushort* QptL = (ushort*)(ws + (size_t)8388608);
  ushort* KptH = (ushort*)(ws + (size_t)16777216);
  ushort* KptL = (ushort*)(ws + (size_t)25165824);
  float*  am0  = (float*) (ws + (size_t)33554432);
  float*  Vp   = (float*) (ws + (size_t)50331648);
  float*  oa   = (float*) (ws + (size_t)50364416);

  // ---- host-side deterministic RNG config (partitionable threefry) ----
  uint32_t kp0, kp1, km0, km1, kr10, kr11, kr20, kr21, a, bbits;
  tf2x32(0u, 42u, 0u, 0u, kp0, kp1);
  tf2x32(0u, 42u, 0u, 1u, km0, km1);
  tf2x32(0u, 42u, 0u, 2u, kr10, kr11);
  tf2x32(0u, 42u, 0u, 3u, kr20, kr21);
  tf2x32(kp0, kp1, 0u, 0u, a, bbits);
  float p = bits2u01(a ^ bbits);
  if (p < 0.f) p = 0.f;
  bool mutate = (p <= 0.6f);

  // 4 dispatches, zero memsets, zero atomics
  lin4<<<544, 256, 0, stream>>>(Q, WQ_w, WQ_b, QptH, QptL,
                                K, WK_w, WK_b, KptH, KptL,
                                V, WV_w, WV_b, Vp);
  am3<<<256, 256, 0, stream>>>(QptH, QptL, KptH, KptL, am0);
  if (mutate) {
    soft_mut<<<2048, 256, 0, stream>>>(am0, Vp, oa, km0, km1);
  } else {
    CrossCfg cfg;
    uint32_t c0, c1;
    tf2x32(kr10, kr11, 0u, 1u, c0, c1);
    for (int t = 0; t < B_ * H_; ++t) {
      tf2x32(c0, c1, 0u, (uint32_t)t, a, bbits);
      cfg.r1[t] = (int)((a ^ bbits) & 511u);
    }
    tf2x32(kr20, kr21, 0u, 1u, c0, c1);
    for (int t = 0; t < B_ * H_; ++t) {
      tf2x32(c0, c1, 0u, (uint32_t)t, a, bbits);
      cfg.r2[t] = (int)((a ^ bbits) & 511u);
    }
    soft_cross<<<16384, 256, 0, stream>>>(am0, Vp, oa, cfg);
  }
  final_gemm<<<32, 256, 0, stream>>>(oa, WO_w, WO_b, out);
}

// Round 13
// 220.103 us; speedup vs baseline: 1.2707x; 1.2707x over previous
//
#include <hip/hip_runtime.h>
#include <stdint.h>
#include <string.h>

// B=16, A=512, H=8, c = 512 - int(512*0.3) = 359
#define B_ 16
#define A_ 512
#define H_ 8
#define C_CROSS 359
#define LDSTRIDE 40  // ushorts per 32-k LDS row (80 B)

typedef short short8 __attribute__((ext_vector_type(8)));
typedef float floatx4 __attribute__((ext_vector_type(4)));

// ---------------- threefry2x32 (exact JAX partitionable semantics) ----------
__host__ __device__ __forceinline__ uint32_t rotl32(uint32_t x, int r) {
#ifdef __HIP_DEVICE_COMPILE__
  return __builtin_amdgcn_alignbit(x, x, 32 - r);
#else
  return (x << r) | (x >> (32 - r));
#endif
}

__host__ __device__ __forceinline__ void tf2x32(uint32_t k0, uint32_t k1,
                                                uint32_t x0, uint32_t x1,
                                                uint32_t& o0, uint32_t& o1) {
  uint32_t ks2 = k0 ^ k1 ^ 0x1BD11BDAu;
  x0 += k0; x1 += k1;
#define TFR(r) { x0 += x1; x1 = rotl32(x1, r); x1 ^= x0; }
  TFR(13) TFR(15) TFR(26) TFR(6)   x0 += k1;  x1 += ks2 + 1u;
  TFR(17) TFR(29) TFR(16) TFR(24)  x0 += ks2; x1 += k0 + 2u;
  TFR(13) TFR(15) TFR(26) TFR(6)   x0 += k0;  x1 += k1 + 3u;
  TFR(17) TFR(29) TFR(16) TFR(24)  x0 += k1;  x1 += ks2 + 4u;
  TFR(13) TFR(15) TFR(26) TFR(6)   x0 += ks2; x1 += k0 + 5u;
#undef TFR
  o0 = x0; o1 = x1;
}

__host__ __device__ __forceinline__ float bits2u01(uint32_t bits) {
  uint32_t v = (bits >> 9) | 0x3f800000u;
  float f;
#ifdef __HIP_DEVICE_COMPILE__
  f = __uint_as_float(v);
#else
  memcpy(&f, &v, 4);
#endif
  return f - 1.0f;
}

__device__ __forceinline__ float exp2_native(float x) {
  float r;
  asm("v_exp_f32 %0, %1\n\ts_nop 0" : "=v"(r) : "v"(x));
  return r;
}

// ---------------- truncation-split bf16 helpers ----------------
__device__ __forceinline__ void tsplit8(const float4& v0, const float4& v1,
                                        short8& h, short8& l) {
  float xs[8] = {v0.x, v0.y, v0.z, v0.w, v1.x, v1.y, v1.z, v1.w};
#pragma unroll
  for (int j = 0; j < 8; ++j) {
    uint32_t u = __float_as_uint(xs[j]);
    float hf = __uint_as_float(u & 0xffff0000u);
    h[j] = (short)(u >> 16);
    l[j] = (short)(__float_as_uint(xs[j] - hf) >> 16);
  }
}

// =====================================================================
// lin4: blocks 0..511 = 128x128 GEMM tile (X and W split in-kernel,
// register double-buffered); output TRANSPOSED + PRE-SPLIT bf16 hi/lo.
// blocks 512..543 = Vp GEMV (full-K, register acc, no atomics).
// =====================================================================
__global__ __launch_bounds__(256, 2) void lin4(
    const float* __restrict__ Xq, const float* __restrict__ Wq,
    const float* __restrict__ bq, ushort* __restrict__ QptH, ushort* __restrict__ QptL,
    const float* __restrict__ Xk, const float* __restrict__ Wk,
    const float* __restrict__ bk, ushort* __restrict__ KptH, ushort* __restrict__ KptL,
    const float* __restrict__ V, const float* __restrict__ WV_w,
    const float* __restrict__ WV_b, float* __restrict__ Vp) {
  __shared__ __align__(16) char smem[40960];
  int bid = blockIdx.x;
  int tid = threadIdx.x;

  if (bid >= 512) {
    // ---- Vp tail: Vp[b][j0+j] = WV_b[j0+j] + sum_k V[b][k]*WV_w[j0+j][k]
    int v = bid - 512;  // 0..31
    int j0 = v * 16;
    float* xs = (float*)smem;            // 16*260 floats
    float* wsh = (float*)(smem + 16640); // 16*260 floats
    int b = tid & 15, j = tid >> 4;
    float acc = WV_b[j0 + j];
    for (int kc = 0; kc < 2; ++kc) {
      int k0 = kc * 256;
      __syncthreads();
#pragma unroll
      for (int it = 0; it < 4; ++it) {
        int idx = it * 256 + tid;
        int rr = idx >> 6, kk4 = idx & 63;
        *(float4*)&xs[rr * 260 + kk4 * 4] =
            *(const float4*)(V + (size_t)rr * 512 + k0 + kk4 * 4);
        *(float4*)&wsh[rr * 260 + kk4 * 4] =
            *(const float4*)(WV_w + (size_t)(j0 + rr) * 512 + k0 + kk4 * 4);
      }
      __syncthreads();
      const float* xr = &xs[b * 260];
      const float* wr = &wsh[j * 260];
#pragma unroll
      for (int kk = 0; kk < 256; kk += 4) {
        float4 a = *(const float4*)(xr + kk);
        float4 w4 = *(const float4*)(wr + kk);
        acc += a.x * w4.x + a.y * w4.y + a.z * w4.z + a.w * w4.w;
      }
    }
    Vp[b * 512 + j0 + j] = acc;
    return;
  }

  // ---- GEMM tile ----
  int z = bid >> 8;
  int rem = bid & 255;
  int ti = rem >> 2, tn = rem & 3;
  const float* X = z ? Xk : Xq;
  const float* W = z ? Wk : Wq;
  const float* bias = z ? bk : bq;
  ushort* OH = z ? KptH : QptH;
  ushort* OL = z ? KptL : QptL;

  ushort (*Ah)[LDSTRIDE] = (ushort(*)[LDSTRIDE])(smem);
  ushort (*Al)[LDSTRIDE] = (ushort(*)[LDSTRIDE])(smem + 10240);
  ushort (*Bh)[LDSTRIDE] = (ushort(*)[LDSTRIDE])(smem + 20480);
  ushort (*Bl)[LDSTRIDE] = (ushort(*)[LDSTRIDE])(smem + 30720);
  uint32_t (*cs)[132] = (uint32_t(*)[132])(smem);  // epilogue alias

  int w = tid >> 6, lane = tid & 63, quad = lane >> 4, l16 = lane & 15;
  int wm = (w >> 1) * 64, wn = (w & 1) * 64;
  int m0 = ti * 128, n0 = tn * 128;

  float bv[4];
#pragma unroll
  for (int nt = 0; nt < 4; ++nt) bv[nt] = bias[n0 + wn + nt * 16 + l16];

  const float* pX[2];
  const float* pW[2];
  int mW[2], kgW[2];
#pragma unroll
  for (int g = 0; g < 2; ++g) {
    int gid = g * 256 + tid;
    int m = gid >> 2, kg = gid & 3;
    mW[g] = m; kgW[g] = kg;
    pX[g] = X + (size_t)(m0 + m) * 512 + kg * 8;
    pW[g] = W + (size_t)(n0 + m) * 512 + kg * 8;
  }

  float4 ra[2][2], rb[2][2];
#pragma unroll
  for (int g = 0; g < 2; ++g) {
    ra[g][0] = *(const float4*)(pX[g]);
    ra[g][1] = *(const float4*)(pX[g] + 4);
    rb[g][0] = *(const float4*)(pW[g]);
    rb[g][1] = *(const float4*)(pW[g] + 4);
  }

  floatx4 acc[4][4] = {};

  for (int k0 = 0; k0 < 512; k0 += 32) {
    __syncthreads();
#pragma unroll
    for (int g = 0; g < 2; ++g) {
      short8 h8, l8;
      tsplit8(ra[g][0], ra[g][1], h8, l8);
      *(short8*)&Ah[mW[g]][kgW[g] * 8] = h8;
      *(short8*)&Al[mW[g]][kgW[g] * 8] = l8;
      tsplit8(rb[g][0], rb[g][1], h8, l8);
      *(short8*)&Bh[mW[g]][kgW[g] * 8] = h8;
      *(short8*)&Bl[mW[g]][kgW[g] * 8] = l8;
    }
    __syncthreads();
    if (k0 < 480) {
      int kn = k0 + 32;
#pragma unroll
      for (int g = 0; g < 2; ++g) {
        ra[g][0] = *(const float4*)(pX[g] + kn);
        ra[g][1] = *(const float4*)(pX[g] + kn + 4);
        rb[g][0] = *(const float4*)(pW[g] + kn);
        rb[g][1] = *(const float4*)(pW[g] + kn + 4);
      }
    }
    short8 fAh[4], fAl[4], fBh[4], fBl[4];
#pragma unroll
    for (int t4 = 0; t4 < 4; ++t4) {
      int ma = wm + t4 * 16 + l16;
      int nb = wn + t4 * 16 + l16;
      fAh[t4] = *(const short8*)&Ah[ma][quad * 8];
      fAl[t4] = *(const short8*)&Al[ma][quad * 8];
      fBh[t4] = *(const short8*)&Bh[nb][quad * 8];
      fBl[t4] = *(const short8*)&Bl[nb][quad * 8];
    }
#pragma unroll
    for (int mt = 0; mt < 4; ++mt)
#pragma unroll
      for (int nt = 0; nt < 4; ++nt) {
        acc[mt][nt] = __builtin_amdgcn_mfma_f32_16x16x32_bf16(fAh[mt], fBh[nt], acc[mt][nt], 0, 0, 0);
        acc[mt][nt] = __builtin_amdgcn_mfma_f32_16x16x32_bf16(fAh[mt], fBl[nt], acc[mt][nt], 0, 0, 0);
        acc[mt][nt] = __builtin_amdgcn_mfma_f32_16x16x32_bf16(fAl[mt], fBh[nt], acc[mt][nt], 0, 0, 0);
      }
  }

  __syncthreads();
  int bb = m0 >> 9, i0 = m0 & 511;
  for (int p = 0; p < 2; ++p) {
    if ((w & 1) == p) {
#pragma unroll
      for (int mt = 0; mt < 4; ++mt)
#pragma unroll
        for (int nt = 0; nt < 4; ++nt)
#pragma unroll
          for (int rr = 0; rr < 4; ++rr) {
            float val = acc[mt][nt][rr] + bv[nt];
            uint32_t u = __float_as_uint(val);
            uint32_t hi = u & 0xffff0000u;
            uint32_t lo = __float_as_uint(val - __uint_as_float(hi)) >> 16;
            cs[nt * 16 + l16][wm + mt * 16 + quad * 4 + rr] = hi | lo;
          }
    }
    __syncthreads();
    {
      int col_l = tid >> 2, iseg = (tid & 3) * 32;
      int d = n0 + p * 64 + col_l;
      size_t obase = ((size_t)(bb * 512 + d)) * 512 + i0 + iseg;
      ushort* oh = OH + obase;
      ushort* ol = OL + obase;
#pragma unroll
      for (int sgi = 0; sgi < 4; ++sgi) {
        short8 hv, lv;
#pragma unroll
        for (int j = 0; j < 8; ++j) {
          uint32_t v = cs[col_l][iseg + sgi * 8 + j];
          hv[j] = (short)(v >> 16);
          lv[j] = (short)(v & 0xffffu);
        }
        *(short8*)(oh + sgi * 8) = hv;
        *(short8*)(ol + sgi * 8) = lv;
      }
    }
    __syncthreads();
  }
}

// =====================================================================
// am3: am0 = QK^T/sqrt(8); pre-split bf16 inputs; 128x128 tiles,
// XCD-swizzled grid (256); register double-buffered.
// =====================================================================
__global__ __launch_bounds__(256, 2) void am3(
    const ushort* __restrict__ QH, const ushort* __restrict__ QL,
    const ushort* __restrict__ KH, const ushort* __restrict__ KL,
    float* __restrict__ am0) {
  int bid = blockIdx.x;
  int xcd = bid & 7, slot = bid >> 3;
  int bz = xcd + 8 * (slot >> 4);
  int tt = slot & 15, ti = tt >> 2, tk = tt & 3;
  int bm0 = ti * 128, bn0 = tk * 128;
  size_t base = (size_t)bz * 262144;

  __shared__ __align__(16) char smem[40960];
  ushort (*Ah)[LDSTRIDE] = (ushort(*)[LDSTRIDE])(smem);
  ushort (*Al)[LDSTRIDE] = (ushort(*)[LDSTRIDE])(smem + 10240);
  ushort (*Bh)[LDSTRIDE] = (ushort(*)[LDSTRIDE])(smem + 20480);
  ushort (*Bl)[LDSTRIDE] = (ushort(*)[LDSTRIDE])(smem + 30720);

  int tid = threadIdx.x;
  int w = tid >> 6, lane = tid & 63, quad = lane >> 4, l16 = lane & 15;
  int wm = (w >> 1) * 64, wn = (w & 1) * 64;

  const ushort *pAH[2], *pAL[2], *pBH[2], *pBL[2];
  int mW[2], kgW[2];
#pragma unroll
  for (int g = 0; g < 2; ++g) {
    int gid = g * 256 + tid;
    int m = gid >> 2, kg = gid & 3;
    mW[g] = m; kgW[g] = kg;
    size_t offA = base + (size_t)(bm0 + m) * 512 + kg * 8;
    size_t offB = base + (size_t)(bn0 + m) * 512 + kg * 8;
    pAH[g] = QH + offA; pAL[g] = QL + offA;
    pBH[g] = KH + offB; pBL[g] = KL + offB;
  }

  short8 rah[2], ral[2], rbh[2], rbl[2];
#pragma unroll
  for (int g = 0; g < 2; ++g) {
    rah[g] = *(const short8*)(pAH[g]);
    ral[g] = *(const short8*)(pAL[g]);
    rbh[g] = *(const short8*)(pBH[g]);
    rbl[g] = *(const short8*)(pBL[g]);
  }

  floatx4 acc[4][4] = {};

  for (int k0 = 0; k0 < 512; k0 += 32) {
    __syncthreads();
#pragma unroll
    for (int g = 0; g < 2; ++g) {
      *(short8*)&Ah[mW[g]][kgW[g] * 8] = rah[g];
      *(short8*)&Al[mW[g]][kgW[g] * 8] = ral[g];
      *(short8*)&Bh[mW[g]][kgW[g] * 8] = rbh[g];
      *(short8*)&Bl[mW[g]][kgW[g] * 8] = rbl[g];
    }
    __syncthreads();
    if (k0 < 480) {
      int kn = k0 + 32;
#pragma unroll
      for (int g = 0; g < 2; ++g) {
        rah[g] = *(const short8*)(pAH[g] + kn);
        ral[g] = *(const short8*)(pAL[g] + kn);
        rbh[g] = *(const short8*)(pBH[g] + kn);
        rbl[g] = *(const short8*)(pBL[g] + kn);
      }
    }
    short8 fAh[4], fAl[4], fBh[4], fBl[4];
#pragma unroll
    for (int t4 = 0; t4 < 4; ++t4) {
      int ma = wm + t4 * 16 + l16;
      int nb = wn + t4 * 16 + l16;
      fAh[t4] = *(const short8*)&Ah[ma][quad * 8];
      fAl[t4] = *(const short8*)&Al[ma][quad * 8];
      fBh[t4] = *(const short8*)&Bh[nb][quad * 8];
      fBl[t4] = *(const short8*)&Bl[nb][quad * 8];
    }
#pragma unroll
    for (int mt = 0; mt < 4; ++mt)
#pragma unroll
      for (int nt = 0; nt < 4; ++nt) {
        acc[mt][nt] = __builtin_amdgcn_mfma_f32_16x16x32_bf16(fAh[mt], fBh[nt], acc[mt][nt], 0, 0, 0);
        acc[mt][nt] = __builtin_amdgcn_mfma_f32_16x16x32_bf16(fAh[mt], fBl[nt], acc[mt][nt], 0, 0, 0);
        acc[mt][nt] = __builtin_amdgcn_mfma_f32_16x16x32_bf16(fAl[mt], fBh[nt], acc[mt][nt], 0, 0, 0);
      }
  }
  const float scale = 0.35355339059327373f;  // 1/sqrt(8)
#pragma unroll
  for (int mt = 0; mt < 4; ++mt)
#pragma unroll
    for (int nt = 0; nt < 4; ++nt)
#pragma unroll
      for (int rr = 0; rr < 4; ++rr) {
        int row = bm0 + wm + mt * 16 + quad * 4 + rr;
        int col = bn0 + wn + nt * 16 + l16;
        am0[((size_t)(bz * 512 + row)) * 512 + col] = acc[mt][nt][rr] * scale;
      }
}

// ---------------- soft_mut: wave per (b,i) row, all 8 heads, inline hash ----
__global__ __launch_bounds__(256) void soft_mut(
    const float* __restrict__ am0, const float* __restrict__ Vp,
    float* __restrict__ oa, uint32_t km0, uint32_t km1) {
  int tid = threadIdx.x;
  int w = tid >> 6, lane = tid & 63;
  int rrow = blockIdx.x * 4 + w;  // b*512 + i
  int b = rrow >> 9, i = rrow & 511;
  int k0 = lane * 8;
  const float* ar = am0 + (((size_t)rrow) << 9) + k0;
  const float* vr = Vp + (b << 9) + k0;
  float4 a0 = *(const float4*)ar, a1 = *(const float4*)(ar + 4);
  float4 v0 = *(const float4*)vr, v1 = *(const float4*)(vr + 4);
  const float LOG2E = 1.4426950408889634f;
  float a2[8] = {a0.x * LOG2E, a0.y * LOG2E, a0.z * LOG2E, a0.w * LOG2E,
                 a1.x * LOG2E, a1.y * LOG2E, a1.z * LOG2E, a1.w * LOG2E};
  float vv[8] = {v0.x, v0.y, v0.z, v0.w, v1.x, v1.y, v1.z, v1.w};
  uint32_t Lbase = (uint32_t)b * 2097152u + (uint32_t)i * 512u + (uint32_t)k0;
  float outv[8];
#pragma unroll
  for (int h = 0; h < 8; ++h) {
    uint32_t Lh = Lbase + (uint32_t)h * 262144u;
    float s = 0.f, wsum = 0.f;
#pragma unroll
    for (int j = 0; j < 8; ++j) {  // 8 independent threefry chains -> ILP
      uint32_t o0, o1;
      tf2x32(km0, km1, 0u, Lh + (uint32_t)j, o0, o1);
      uint32_t bits = o0 ^ o1;
      float f = __uint_as_float((bits >> 9) | 0x3f800000u);
      float m = fmaxf(0.7f, __builtin_fmaf(f, 0.6f, 0.1f));
      float e = exp2_native(a2[j] * m);
      s += e;
      wsum += e * vv[j];
    }
#pragma unroll
    for (int o = 32; o; o >>= 1) { s += __shfl_xor(s, o); wsum += __shfl_xor(wsum, o); }
    outv[h] = wsum / s;
  }
  if (lane == 0) {
    int ob = (b << 12) + i;
#pragma unroll
    for (int h = 0; h < 8; ++h) oa[ob + (h << 9)] = outv[h];
  }
}

// ---------------- soft_cross ----------------
struct CrossCfg { int r1[B_ * H_]; int r2[B_ * H_]; };

__global__ __launch_bounds__(256) void soft_cross(
    const float* __restrict__ am0, const float* __restrict__ Vp,
    float* __restrict__ oa, CrossCfg cfg) {
  int tid = threadIdx.x;
  int w = tid >> 6, lane = tid & 63;
  int rrow = blockIdx.x * 4 + w;
  int b = rrow >> 12, h = (rrow >> 9) & 7, i = rrow & 511;
  int rr1 = cfg.r1[b * 8 + h], rr2 = cfg.r2[b * 8 + h];
  int src = (i == rr2) ? rr1 : ((i == rr1) ? rr2 : i);
  const float* ar = am0 + ((size_t)((b << 9) + i)) * A_;
  const float* ar2 = am0 + ((size_t)((b << 9) + src)) * A_;
  const float* vr = Vp + (b << 9);
  float s = 0.f, wsum = 0.f;
#pragma unroll
  for (int j = 0; j < 8; ++j) {
    int k = lane + 64 * j;
    float x = (k >= C_CROSS) ? ar2[k] : ar[k];
    float e = __expf(x);
    s += e;
    wsum += e * vr[k];
  }
#pragma unroll
  for (int o = 32; o; o >>= 1) { s += __shfl_xor(s, o); wsum += __shfl_xor(wsum, o); }
  if (lane == 0) oa[(((size_t)(b * 8 + h)) << 9) + i] = wsum / s;
}

// =====================================================================
// final_small: out[b][j0+j] += sum_{k chunk} oa[b][k]*WO[j0+j][k] (+bias @y0)
// grid (32,16) = 512 blocks; atomicAdd; out pre-zeroed. Proven ~10 us.
// =====================================================================
__global__ __launch_bounds__(256) void final_small(
    const float* __restrict__ X, const float* __restrict__ W,
    const float* __restrict__ bias, float* __restrict__ out) {
  __shared__ float xs[16 * 260];
  __shared__ float wsh[16 * 260];
  int tid = threadIdx.x;
  int j0 = blockIdx.x * 16;
  int k0 = blockIdx.y * 256;
#pragma unroll
  for (int it = 0; it < 4; ++it) {
    int idx = it * 256 + tid;
    int rr = idx >> 6, kk4 = idx & 63;
    *(float4*)&xs[rr * 260 + kk4 * 4] =
        *(const float4*)(X + (size_t)rr * 4096 + k0 + kk4 * 4);
    *(float4*)&wsh[rr * 260 + kk4 * 4] =
        *(const float4*)(W + (size_t)(j0 + rr) * 4096 + k0 + kk4 * 4);
  }
  __syncthreads();
  int b = tid & 15, j = tid >> 4;
  const float* xr = &xs[b * 260];
  const float* wr = &wsh[j * 260];
  float acc = 0.f;
#pragma unroll
  for (int kk = 0; kk < 256; kk += 4) {
    float4 a = *(const float4*)(xr + kk);
    float4 w4 = *(const float4*)(wr + kk);
    acc += a.x * w4.x + a.y * w4.y + a.z * w4.z + a.w * w4.w;
  }
  if (blockIdx.y == 0) acc += bias[j0 + j];
  atomicAdd(&out[b * 512 + j0 + j], acc);
}

extern "C" void kernel_launch(void* const* d_in, const int* in_sizes, int n_in,
                              void* d_out, int out_size, void* d_ws, size_t ws_size,
                              hipStream_t stream) {
  (void)in_sizes; (void)n_in; (void)out_size; (void)ws_size;
  const float* Q    = (const float*)d_in[0];
  const float* K    = (const float*)d_in[1];
  const float* V    = (const float*)d_in[2];
  const float* WQ_w = (const float*)d_in[3];
  const float* WQ_b = (const float*)d_in[4];
  const float* WK_w = (const float*)d_in[5];
  const float* WK_b = (const float*)d_in[6];
  const float* WV_w = (const float*)d_in[7];
  const float* WV_b = (const float*)d_in[8];
  const float* WO_w = (const float*)d_in[9];
  const float* WO_b = (const float*)d_in[10];
  float* out = (float*)d_out;

  // ws: QptH/QptL/KptH/KptL (4 x 8.39MB) + am0 (16.78MB) + Vp(32KB) + oa(256KB)
  //   = 50.66MB
  char* ws = (char*)d_ws;
  ushort* QptH = (ushort*)(ws);
  ushort* QptL = (ushort*)(ws + (size_t)8388608);
  ushort* KptH = (ushort*)(ws + (size_t)16777216);
  ushort* KptL = (ushort*)(ws + (size_t)25165824);
  float*  am0  = (float*) (ws + (size_t)33554432);
  float*  Vp   = (float*) (ws + (size_t)50331648);
  float*  oa   = (float*) (ws + (size_t)50364416);

  // ---- host-side deterministic RNG config (partitionable threefry) ----
  uint32_t kp0, kp1, km0, km1, kr10, kr11, kr20, kr21, a, bbits;
  tf2x32(0u, 42u, 0u, 0u, kp0, kp1);
  tf2x32(0u, 42u, 0u, 1u, km0, km1);
  tf2x32(0u, 42u, 0u, 2u, kr10, kr11);
  tf2x32(0u, 42u, 0u, 3u, kr20, kr21);
  tf2x32(kp0, kp1, 0u, 0u, a, bbits);
  float p = bits2u01(a ^ bbits);
  if (p < 0.f) p = 0.f;
  bool mutate = (p <= 0.6f);

  hipMemsetAsync(out, 0, 16 * 512 * sizeof(float), stream);
  lin4<<<544, 256, 0, stream>>>(Q, WQ_w, WQ_b, QptH, QptL,
                                K, WK_w, WK_b, KptH, KptL,
                                V, WV_w, WV_b, Vp);
  am3<<<256, 256, 0, stream>>>(QptH, QptL, KptH, KptL, am0);
  if (mutate) {
    soft_mut<<<2048, 256, 0, stream>>>(am0, Vp, oa, km0, km1);
  } else {
    CrossCfg cfg;
    uint32_t c0, c1;
    tf2x32(kr10, kr11, 0u, 1u, c0, c1);
    for (int t = 0; t < B_ * H_; ++t) {
      tf2x32(c0, c1, 0u, (uint32_t)t, a, bbits);
      cfg.r1[t] = (int)((a ^ bbits) & 511u);
    }
    tf2x32(kr20, kr21, 0u, 1u, c0, c1);
    for (int t = 0; t < B_ * H_; ++t) {
      tf2x32(c0, c1, 0u, (uint32_t)t, a, bbits);
      cfg.r2[t] = (int)((a ^ bbits) & 511u);
    }
    soft_cross<<<16384, 256, 0, stream>>>(am0, Vp, oa, cfg);
  }
  final_small<<<dim3(32, 16), 256, 0, stream>>>(oa, WO_w, WO_b, out);
}